// Round 3
// 466.161 us; speedup vs baseline: 1.0542x; 1.0542x over previous
//
#include <hip/hip_runtime.h>

// GRU cell, B=16384, E=H=1024. fp32 in/out, bf16 MFMA compute.
//
// R6 = R5 resubmitted after audit (R1/R2 benches died to container failures,
// no counters; audit found no hang/race/OOB mechanism — see ledger below).
//   pre:  cast x,h -> bf16;  6 weights -> transposed bf16, Z/R stacked to N=2048
//   ZR:   [x|h](16384x2048) @ Bzr^T(2048x2048) -> ztb=bf16(sigmoid), ab=bf16(h*sigmoid)
//   H:    [x|ab](16384x2048) @ Wh^T(1024x2048) -> out = h + z*(tanh-h), fp32
// GEMM: 256x256 tile, BK=64, 512 thr / 8 waves (2Mx4N), per-wave 128x64,
// acc[8][4] f32x4. LDS 128 KiB: A,B each [2 dbuf][2 khalf][256][32] bf16.
// 4 phases/tile = (M-half, K-slice): p0=mi0-3/k0 p1=mi4-7/k0 p2=mi0-3/k1
// p3=mi4-7/k1. kh0 slots fully read after p1, kh1 after p3 -> staging:
//   p0: A(kt+1,kh1)  p1: B(kt+1,kh1)  p2: A(kt+2,kh0)  p3: B(kt+2,kh0)
// (kt+2 kh0 lands in THIS tile's just-freed kh0 slots -> no race with 2 bufs).
// vmcnt(4) at p1 and p3 (4 loads always in flight; never drained in main loop).
// Ledger (per-wave outstanding, oldest first), steady state at tile kt entry:
//   [A(kt+1,0) B(kt+1,0)]; p0 +A(kt+1,1); p1 +B(kt+1,1), vm4 => kt+1 kh0 landed;
//   p2 +A(kt+2,0); p3 +B(kt+2,0), vm4 => kt+1 kh1 landed. Tiles 30/31 peeled.
// Swizzle for [256][32] rows (64B stride): 16B chunk ^= (row>>1)&3; per
// ds_read_b128 the 256 words spread exactly 8/bank (conflict-free floor).
// Applied inverse on global_load_lds source col, forward on ds_read col;
// read-side row term reduces to (l4>>1)&3 so fragment offsets are immediates.

typedef short bf16x8 __attribute__((ext_vector_type(8)));
typedef float f32x4 __attribute__((ext_vector_type(4)));

template <int V> struct Ic { static constexpr int value = V; };

static __device__ __forceinline__ unsigned short f2bf(float f) {
    unsigned int u = __float_as_uint(f);
    return (unsigned short)((u + 0x7fffu + ((u >> 16) & 1u)) >> 16);
}
static __device__ __forceinline__ float bf2f(unsigned short s) {
    return __uint_as_float(((unsigned int)s) << 16);
}

// ---- cast x and h to bf16 in one launch ------------------------------------
__global__ void cast2_f32_bf16(const float* __restrict__ a,
                               const float* __restrict__ b,
                               unsigned short* __restrict__ da,
                               unsigned short* __restrict__ db, int n) {
    int i = (blockIdx.x * blockDim.x + threadIdx.x) * 4;
    const float* s;
    unsigned short* d;
    int off;
    if (i < n) { s = a; d = da; off = i; }
    else       { s = b; d = db; off = i - n; }
    float4 v = *(const float4*)(s + off);
    ushort4 o;
    o.x = f2bf(v.x); o.y = f2bf(v.y); o.z = f2bf(v.z); o.w = f2bf(v.w);
    *(ushort4*)(d + off) = o;
}

// ---- transpose+cast all 6 weights in one launch ----------------------------
struct TPlan {
    const float* src[6];
    unsigned short* dst[6];  // pre-offset; row stride 2048
};
__global__ void transpose_cast6(TPlan p) {
    __shared__ float t[32][33];
    const float* src = p.src[blockIdx.z];
    unsigned short* dst = p.dst[blockIdx.z];
    int bx = blockIdx.x, by = blockIdx.y;
    int tx = threadIdx.x, ty = threadIdx.y;  // 32 x 8
#pragma unroll
    for (int i = 0; i < 4; ++i)
        t[ty + 8 * i][tx] = src[(by * 32 + ty + 8 * i) * 1024 + bx * 32 + tx];
    __syncthreads();
#pragma unroll
    for (int i = 0; i < 4; ++i) {
        int n = bx * 32 + ty + 8 * i;  // dst row (N)
        int k = by * 32 + tx;          // dst col (K)
        dst[n * 2048 + k] = f2bf(t[tx][ty + 8 * i]);
    }
}

// ---- fused GEMM, 256x256, K-half-recycled 4-phase schedule ------------------
// MODE 0 (ZR): N=2048 (cols 0-1023 = z gate, 1024-2047 = r gate)
// MODE 1 (H):  N=1024
template <int MODE, int NBN_LOG>
__global__ __launch_bounds__(512, 2) void gemm_gru(
        const unsigned short* __restrict__ Alo,  // k in [0,1024), stride 1024
        const unsigned short* __restrict__ Ahi,  // k in [1024,2048), stride 1024
        const unsigned short* __restrict__ Bt,   // [N][2048]
        const float* __restrict__ bias_z,
        const float* __restrict__ bias_r,
        const unsigned short* __restrict__ hb,   // bf16 h
        const unsigned short* __restrict__ ztb_in,
        const float* __restrict__ hf,            // fp32 h
        unsigned short* __restrict__ ztb_out,
        unsigned short* __restrict__ ab_out,
        float* __restrict__ out) {
    constexpr int NBN = 1 << NBN_LOG;
    constexpr int NT = 32;  // 2048 / 64
    // [dbuf][khalf][256 rows][32 cols] bf16 = 16 KB per half-slot
    __shared__ __attribute__((aligned(16))) short As[2][2][256 * 32];
    __shared__ __attribute__((aligned(16))) short Bs[2][2][256 * 32];

    const int t = threadIdx.x;
    const int lane = t & 63;
    const int wave = t >> 6;
    const int wm = wave >> 2, wn = wave & 3;  // 2M x 4N

    // XCD swizzle: all NBN bn-blocks of one bm A-panel are stride-8 in
    // blockIdx -> same XCD L2. nwg % 8 == 0 -> bijective.
    const int i = blockIdx.x;
    const int bml = i & 7;
    const int bn = (i >> 3) & (NBN - 1);
    const int bmg = i >> (3 + NBN_LOG);
    const int bm = bmg * 8 + bml;

    const int l4 = lane & 15, kg = lane >> 4;
    // ds_read element col with swizzle: chunk kg ^ ((row>>1)&3); row-term
    // reduces to (l4>>1)&3 for all fragments (mi*16, wm*128 etc. == 0 mod 4).
    const int rdcol = ((kg ^ ((l4 >> 1) & 3)) * 8);
    const int aoff = (wm * 128 + l4) * 32 + rdcol;
    const int boff = (wn * 64 + l4) * 32 + rdcol;

    // staging: thread t, chunk j -> LDS row j*128 + (t>>2), chunk t&3.
    // inverse swizzle on global source col: chunk (t&3) ^ ((t>>3)&3).
    const int srow = t >> 2;                          // 0..127
    const int scol = (((t & 3) ^ ((t >> 3) & 3)) * 8);  // 0..24
    const int rowA0 = bm * 256;
    const int rowB0 = bn * 256;

    f32x4 acc[8][4] = {};
    bf16x8 bfr[4];  // B fragments for current K-slice (read at p0/p2, reused p1/p3)

    // one half-tile = 256 rows x 32 cols = 16 KB = 2 loads/thread
    auto stage_half = [&](const unsigned short* src, int stride, int grow0,
                          int kcol, short* dst) {
#pragma unroll
        for (int j = 0; j < 2; ++j) {
            const unsigned short* g =
                src + (size_t)(grow0 + j * 128 + srow) * stride + (kcol + scol);
            __builtin_amdgcn_global_load_lds(
                (const __attribute__((address_space(1))) void*)g,
                (__attribute__((address_space(3))) void*)(dst + (j * 512 + wave * 64) * 8),
                16, 0, 0);
        }
    };
    auto stage_A = [&](int T, int s) {
        const unsigned short* Ab = (T < 16) ? Alo : Ahi;
        stage_half(Ab, 1024, rowA0, ((T * 64) & 1023) + s * 32, &As[T & 1][s][0]);
    };
    auto stage_B = [&](int T, int s) {
        stage_half(Bt, 2048, rowB0, T * 64 + s * 32, &Bs[T & 1][s][0]);
    };

    auto nop = [] {};
    auto vm4 = [] { asm volatile("s_waitcnt vmcnt(4)" ::: "memory"); };
    auto vm0 = [] { asm volatile("s_waitcnt vmcnt(0)" ::: "memory"); };

    // Phase: ds_read subtile | issue stage -> barrier -> lgkmcnt(0) ->
    // setprio(1) 16 MFMA setprio(0) -> counted vmcnt -> barrier.
    auto phase = [&](auto dC, auto mC, auto sC, auto stage, auto vmw) {
        constexpr int d = decltype(dC)::value;
        constexpr int m0 = decltype(mC)::value;
        constexpr int s = decltype(sC)::value;
        const short* Ab = &As[d][s][aoff];
        const short* Bb = &Bs[d][s][boff];
        bf16x8 af0 = *(const bf16x8*)(Ab + (m0 + 0) * 512);
        bf16x8 af1 = *(const bf16x8*)(Ab + (m0 + 1) * 512);
        bf16x8 af2 = *(const bf16x8*)(Ab + (m0 + 2) * 512);
        bf16x8 af3 = *(const bf16x8*)(Ab + (m0 + 3) * 512);
        if constexpr (m0 == 0) {
#pragma unroll
            for (int ni = 0; ni < 4; ++ni)
                bfr[ni] = *(const bf16x8*)(Bb + ni * 512);
        }
        stage();
        __builtin_amdgcn_s_barrier();
        asm volatile("s_waitcnt lgkmcnt(0)" ::: "memory");
        __builtin_amdgcn_s_setprio(1);
#pragma unroll
        for (int ni = 0; ni < 4; ++ni) {
            acc[m0 + 0][ni] = __builtin_amdgcn_mfma_f32_16x16x32_bf16(
                af0, bfr[ni], acc[m0 + 0][ni], 0, 0, 0);
            acc[m0 + 1][ni] = __builtin_amdgcn_mfma_f32_16x16x32_bf16(
                af1, bfr[ni], acc[m0 + 1][ni], 0, 0, 0);
        }
#pragma unroll
        for (int ni = 0; ni < 4; ++ni) {
            acc[m0 + 2][ni] = __builtin_amdgcn_mfma_f32_16x16x32_bf16(
                af2, bfr[ni], acc[m0 + 2][ni], 0, 0, 0);
            acc[m0 + 3][ni] = __builtin_amdgcn_mfma_f32_16x16x32_bf16(
                af3, bfr[ni], acc[m0 + 3][ni], 0, 0, 0);
        }
        __builtin_amdgcn_s_setprio(0);
        vmw();
        __builtin_amdgcn_s_barrier();
    };

    // Prologue: tile0 (4 halves) + tile1 kh0 (2 halves) = 12 loads.
    stage_A(0, 0); stage_B(0, 0); stage_A(0, 1); stage_B(0, 1);
    stage_A(1, 0); stage_B(1, 0);
    asm volatile("s_waitcnt vmcnt(4)" ::: "memory");  // tile0 landed; tile1-kh0 in flight
    __builtin_amdgcn_s_barrier();

    auto tile = [&](auto dC, int kt) {
        phase(dC, Ic<0>{}, Ic<0>{}, [&] { stage_A(kt + 1, 1); }, nop);
        phase(dC, Ic<4>{}, Ic<0>{}, [&] { stage_B(kt + 1, 1); }, vm4);
        phase(dC, Ic<0>{}, Ic<1>{}, [&] { stage_A(kt + 2, 0); }, nop);
        phase(dC, Ic<4>{}, Ic<1>{}, [&] { stage_B(kt + 2, 0); }, vm4);
    };

    for (int kt = 0; kt < NT - 2; kt += 2) {
        tile(Ic<0>{}, kt);
        tile(Ic<1>{}, kt + 1);
    }
    // Tile NT-2 (=30, d=0): only tile31-kh1 left to stage; then drain.
    phase(Ic<0>{}, Ic<0>{}, Ic<0>{}, [&] { stage_A(NT - 1, 1); }, nop);
    phase(Ic<0>{}, Ic<4>{}, Ic<0>{}, [&] { stage_B(NT - 1, 1); }, vm4);
    phase(Ic<0>{}, Ic<0>{}, Ic<1>{}, nop, nop);
    phase(Ic<0>{}, Ic<4>{}, Ic<1>{}, nop, vm0);
    // Tile NT-1 (=31, d=1): pure compute.
    phase(Ic<1>{}, Ic<0>{}, Ic<0>{}, nop, nop);
    phase(Ic<1>{}, Ic<4>{}, Ic<0>{}, nop, nop);
    phase(Ic<1>{}, Ic<0>{}, Ic<1>{}, nop, nop);
    phase(Ic<1>{}, Ic<4>{}, Ic<1>{}, nop, nop);

    // Epilogue. C/D layout: col = lane&15, row = (lane>>4)*4 + reg  [m89]
    const int q4 = kg * 4;
#pragma unroll
    for (int mi = 0; mi < 8; ++mi) {
        int row0 = bm * 256 + wm * 128 + mi * 16 + q4;
#pragma unroll
        for (int ni = 0; ni < 4; ++ni) {
            int colg = bn * 256 + wn * 64 + ni * 16 + l4;
            if (MODE == 0) {
                bool isZ = colg < 1024;  // block-uniform (256 | 1024)
                int col = colg & 1023;
                float bz = isZ ? bias_z[col] : bias_r[col];
#pragma unroll
                for (int r = 0; r < 4; ++r) {
                    int idx = (row0 + r) * 1024 + col;
                    float v = acc[mi][ni][r] + bz;
                    float s = 1.0f / (1.0f + __expf(-v));
                    if (isZ) ztb_out[idx] = f2bf(s);
                    else     ab_out[idx] = f2bf(bf2f(hb[idx]) * s);
                }
            } else {
                float bz = bias_z[colg];
#pragma unroll
                for (int r = 0; r < 4; ++r) {
                    int idx = (row0 + r) * 1024 + colg;
                    float v = acc[mi][ni][r] + bz;
                    // tanh, saturation-safe: 1 - 2/(e^{2v}+1)
                    float e = __expf(2.0f * v);
                    float ht = 1.0f - 2.0f / (e + 1.0f);
                    float hv = hf[idx];
                    float z = bf2f(ztb_in[idx]);
                    out[idx] = fmaf(z, ht - hv, hv);
                }
            }
        }
    }
}

extern "C" void kernel_launch(void* const* d_in, const int* in_sizes, int n_in,
                              void* d_out, int out_size, void* d_ws, size_t ws_size,
                              hipStream_t stream) {
    const float* x    = (const float*)d_in[0];
    const float* h    = (const float*)d_in[1];
    const float* W_ri = (const float*)d_in[2];
    const float* b_ri = (const float*)d_in[3];
    const float* W_rh = (const float*)d_in[4];
    const float* W_zi = (const float*)d_in[5];
    const float* b_zi = (const float*)d_in[6];
    const float* W_zh = (const float*)d_in[7];
    const float* W_hi = (const float*)d_in[8];
    const float* b_hi = (const float*)d_in[9];
    const float* W_hh = (const float*)d_in[10];
    float* out = (float*)d_out;

    const size_t MB = 1024ull * 1024ull;
    char* ws = (char*)d_ws;
    unsigned short* xb   = (unsigned short*)(ws);             // 32 MB
    unsigned short* hb   = (unsigned short*)(ws + 32 * MB);   // 32 MB
    unsigned short* ab   = (unsigned short*)(ws + 64 * MB);   // 32 MB
    unsigned short* ztb  = (unsigned short*)(ws + 96 * MB);   // 32 MB
    unsigned short* Bzr  = (unsigned short*)(ws + 128 * MB);  // 8 MB  [2048][2048]
    unsigned short* Bh   = (unsigned short*)(ws + 136 * MB);  // 4 MB  [1024][2048]

    const int NELEM = 16384 * 1024;
    cast2_f32_bf16<<<2 * NELEM / (256 * 4), 256, 0, stream>>>(x, h, xb, hb, NELEM);

    TPlan p;
    p.src[0] = W_zi; p.dst[0] = Bzr + 0 * 2048 + 0;
    p.src[1] = W_zh; p.dst[1] = Bzr + 0 * 2048 + 1024;
    p.src[2] = W_ri; p.dst[2] = Bzr + 1024 * 2048 + 0;
    p.src[3] = W_rh; p.dst[3] = Bzr + 1024 * 2048 + 1024;
    p.src[4] = W_hi; p.dst[4] = Bh + 0;
    p.src[5] = W_hh; p.dst[5] = Bh + 1024;
    transpose_cast6<<<dim3(32, 32, 6), dim3(32, 8), 0, stream>>>(p);

    // ZR: 64 bm * 8 bn = 512 blocks; H: 64 bm * 4 bn = 256 blocks
    gemm_gru<0, 3><<<512, 512, 0, stream>>>(xb, hb, Bzr, b_zi, b_ri,
                                            hb, nullptr, nullptr,
                                            ztb, ab, nullptr);
    gemm_gru<1, 2><<<256, 512, 0, stream>>>(xb, ab, Bh, b_hi, nullptr,
                                            nullptr, ztb, h,
                                            nullptr, nullptr, out);
}